// Round 17
// baseline (102.714 us; speedup 1.0000x reference)
//
#include <hip/hip_runtime.h>
#include <math.h>

#define B 4
#define CIN 64
#define H 128
#define W 128
#define COUT 128
#define KK 9
#define HW (H*W)

#define WBF_COLS 640                 // 4 chunks x 160 (144 real + 16 zero)
#define WBF_SHORTS (COUT*WBF_COLS)
#define WCV_SHORTS (32*640)          // offmask conv weights, bf16, K-padded
#define LDK 168                      // LDS k-stride (shorts); 336B row stride

typedef __attribute__((ext_vector_type(8))) short short8;
typedef __attribute__((ext_vector_type(4))) float f32x4;
typedef __attribute__((ext_vector_type(2))) float f32x2;
typedef __attribute__((ext_vector_type(4))) unsigned int u32x4;
typedef f32x2 __attribute__((aligned(4))) f32x2a;   // align-4 float2 load

// global->LDS DMA: 16B per lane, dest = wave-uniform base + lane*16.
#define GLDS16(g, l) __builtin_amdgcn_global_load_lds(                        \
    (__attribute__((address_space(1))) void*)(g),                             \
    (__attribute__((address_space(3))) void*)(l), 16, 0, 0)

__device__ __forceinline__ unsigned short f2bf(float f) {
    unsigned int u = __float_as_uint(f);
    u += 0x7fffu + ((u >> 16) & 1u);
    return (unsigned short)(u >> 16);
}

// HW packed f32->bf16 convert (RNE), src0 -> bits[15:0], src1 -> bits[31:16].
// 1 instr replaces ~10 (2x manual RNE + short8 element inserts).
__device__ __forceinline__ unsigned int pkbf16(float lo, float hi) {
    unsigned int r;
    asm("v_cvt_pk_bf16_f32 %0, %1, %2" : "=v"(r) : "v"(lo), "v"(hi));
    return r;
}

// ---------------------------------------------------------------------------
// prep_wcv: offmask conv weights -> bf16 wcv[f(32)][cb*160 + tap*16 + ci]
// (rows 27..31 and cols [144,160) zero). Also fills bcat (32 biases).
// ---------------------------------------------------------------------------
__global__ void prep_wcv(const float* __restrict__ w_off, const float* __restrict__ b_off,
                         const float* __restrict__ w_mask, const float* __restrict__ b_mask,
                         short* __restrict__ wcv, float* __restrict__ bcat)
{
    int idx = blockIdx.x * 256 + threadIdx.x;
    if (idx < WCV_SHORTS) {
        int f  = idx / 640;
        int kp = idx % 640;
        int cb = kp / 160, r = kp % 160;
        float v = 0.f;
        if (r < 144) {
            int tap = r >> 4;
            int c   = cb * 16 + (r & 15);
            if (f < 18)      v = w_off[(f * CIN + c) * 9 + tap];
            else if (f < 27) v = w_mask[((f - 18) * CIN + c) * 9 + tap];
        }
        wcv[idx] = (short)f2bf(v);
    }
    if (blockIdx.x == 0 && threadIdx.x < 32) {
        int f = threadIdx.x;
        float bv = 0.f;
        if (f < 18) bv = b_off[f];
        else if (f < 27) bv = b_mask[f - 18];
        bcat[f] = bv;
    }
}

// ---------------------------------------------------------------------------
// prep_wbf: einsum weights -> bf16, layout [o][cb*160 + tap*16 + ci];
// pad cols [144,160) per chunk are ZERO.
// ---------------------------------------------------------------------------
__global__ void prep_wbf(const float* __restrict__ wgt, short* __restrict__ wbf)
{
    int idx = blockIdx.x * 256 + threadIdx.x;
    if (idx >= WBF_SHORTS) return;
    int o  = idx / WBF_COLS;
    int kp = idx % WBF_COLS;
    int cb = kp / 160, r = kp % 160;
    float v = 0.f;
    if (r < 144) {
        int tap = r >> 4;
        int c   = cb * 16 + (r & 15);
        v = wgt[(o * CIN + c) * KK + tap];
    }
    wbf[idx] = (short)f2bf(v);
}

// ---------------------------------------------------------------------------
// fused5 = fused4 (R16, 80.4us) + v_cvt_pk_bf16_f32 convert+pack in buildA
// and sampleB (fast + fallback paths). The manual f2bf + short8 element
// inserts (~10 VALU per value-pair) become 1 cvt_pk per pair + one u32x4
// store -- shortening the per-phase LDS->VALU->LDS dependent chains that
// set the barrier cadence (no pipe >22% busy; latency-bound).
// RNE in both paths -> output expected bit-identical (absmax = tripwire).
// LDS 35,328 B -> 4 blocks/CU. XCD band swizzle; no chunk stagger.
// ---------------------------------------------------------------------------
__global__ __launch_bounds__(256, 2) void fused5_kernel(
    const float* __restrict__ x, const short* __restrict__ wcv,
    const short* __restrict__ wbf, const float* __restrict__ bcat,
    float* __restrict__ out)
{
    const int bid = blockIdx.x;
    const int T = (bid & 7) * 128 + (bid >> 3);
    const int wo0 = (T & 1) * 64;
    const int ho  = (T >> 1) & 127;
    const int b   = T >> 8;
    const int tid  = threadIdx.x;
    const int lane = tid & 63;
    const int wv   = tid >> 6;
    const int oh   = (wv & 1) * 64;
    const int ph   = (wv >> 1) * 32;
    const int row16 = lane & 15, kq = lane >> 4;

    __shared__ __align__(16) float XW[3456];          // 13,824 B
                                                      //  A: [ci16][row3][72]
                                                      //  B: [ci8][row6][72]
    __shared__ __align__(16) short S[64 * LDK];       // 21,504 B
    float* offs_l = (float*)S;                        // phase-A out: 27*64 f32

    const float* xb = x + (size_t)b * CIN * HW;

    // =======================================================================
    // Phase A: 27-filter conv via MFMA, 16-ch chunks (4 chunks of K=144).
    // =======================================================================
    int stA_goff[4];
    #pragma unroll
    for (int t = 0; t < 4; ++t) {
        int idx = tid + t * 256;
        int ci = idx / 54, rem = idx % 54, row = rem / 18, q = rem % 18;
        int ys = min(max(ho - 1 + row, 0), H - 1);
        int g0 = wo0 - 4 + q * 4;
        int g0c = min(max(g0, 0), W - 4);
        stA_goff[t] = ci * HW + ys * W + g0c;
    }
    auto stageA = [&](int c) {        // 864 slots: 16ch x 3row x 18quad
        const float* base = xb + (size_t)c * 16 * HW;
        #pragma unroll
        for (int t = 0; t < 4; ++t) {
            if (tid + t * 256 < 864) {
                GLDS16(base + stA_goff[t], &XW[(tid + t * 256) * 4]);
            }
        }
    };

    if (tid < 128) {                      // zero K-pad [144,160)
        short8 z = {0,0,0,0,0,0,0,0};
        *(short8*)&S[(tid >> 1) * LDK + 144 + (tid & 1) * 8] = z;
    }
    stageA(0);                            // DMA in flight under metadata below

    int bidx[3];                           // im2col src offset; -1 = zero
    #pragma unroll
    for (int j = 0; j < 3; ++j) {
        bidx[j] = -1;
        int s = tid + j * 256;
        if (s < 576) {
            int k = s >> 6, p = s & 63;
            int ky = k / 3, kx = k % 3;
            bool ok = ((unsigned)(ho - 1 + ky) < (unsigned)H)
                   && ((unsigned)(wo0 + p - 1 + kx) < (unsigned)W);
            if (ok) bidx[j] = ky * 72 + (p + 3 + kx);
        }
    }
    // phase-B staging offsets (computed here to hide stageA(0))
    int stB_goff[4];
    #pragma unroll
    for (int t = 0; t < 4; ++t) {
        int idx = tid + t * 256;
        int ci = idx / 108, rem = idx % 108, row = rem / 18, q = rem % 18;
        int ys = min(max(ho - 2 + row, 0), H - 1);
        int g0 = wo0 - 4 + q * 4;
        int g0c = min(max(g0, 0), W - 4);
        stB_goff[t] = ci * HW + ys * W + g0c;
    }
    __syncthreads();                      // XW(A0) ready, pads zeroed

    f32x4 acc2[2];
    acc2[0] = (f32x4){0.f, 0.f, 0.f, 0.f};
    acc2[1] = (f32x4){0.f, 0.f, 0.f, 0.f};

    auto buildA = [&]() {                 // 16 ci per slot (both parities)
        #pragma unroll
        for (int j = 0; j < 3; ++j) {
            int s = tid + j * 256;
            if (s < 576) {
                int k = s >> 6, p = s & 63;
                #pragma unroll
                for (int h2 = 0; h2 < 2; ++h2) {
                    u32x4 pk = {0u, 0u, 0u, 0u};
                    if (bidx[j] >= 0) {
                        const float* bp = &XW[h2 * 8 * 216 + bidx[j]];
                        pk.x = pkbf16(bp[0],    bp[216]);
                        pk.y = pkbf16(bp[432],  bp[648]);
                        pk.z = pkbf16(bp[864],  bp[1080]);
                        pk.w = pkbf16(bp[1296], bp[1512]);
                    }
                    *(u32x4*)&S[p * LDK + k * 16 + h2 * 8] = pk;
                }
            }
        }
    };
    auto mfmaA = [&](int c) {
        #pragma unroll
        for (int ks = 0; ks < 5; ++ks) {
            short8 a0 = *(const short8*)(wcv + (row16)      * 640 + c * 160 + ks * 32 + kq * 8);
            short8 a1 = *(const short8*)(wcv + (16 + row16) * 640 + c * 160 + ks * 32 + kq * 8);
            short8 bfr = *(const short8*)&S[(wv * 16 + row16) * LDK + ks * 32 + kq * 8];
            acc2[0] = __builtin_amdgcn_mfma_f32_16x16x32_bf16(a0, bfr, acc2[0], 0, 0, 0);
            acc2[1] = __builtin_amdgcn_mfma_f32_16x16x32_bf16(a1, bfr, acc2[1], 0, 0, 0);
        }
    };

    buildA();
    __syncthreads();                      // S(0) ready; XW reads done
    #pragma unroll 1
    for (int c = 0; c < 3; ++c) {
        stageA(c + 1);                    // DMA drains under MFMA
        mfmaA(c);
        __syncthreads();                  // DMA done; S reads done
        buildA();
        __syncthreads();                  // S ready; XW reads done
    }
    mfmaA(3);
    __syncthreads();                      // all S reads done -> S reusable

    // conv epilogue: bias + sigmoid -> offs_l (LDS, aliases S)
    {
        const int pxl = wv * 16 + row16;
        #pragma unroll
        for (int of = 0; of < 2; ++of) {
            #pragma unroll
            for (int r = 0; r < 4; ++r) {
                int f = of * 16 + kq * 4 + r;
                if (f < 27) {
                    float v = acc2[of][r] + bcat[f];
                    if (f >= 18) v = 1.f / (1.f + expf(-v));
                    offs_l[f * 64 + pxl] = v;
                }
            }
        }
    }
    __syncthreads();                      // offs_l visible

    // =======================================================================
    // Phase B: deform sample + MFMA einsum, 8-ch halves.
    // =======================================================================
    auto stageB = [&](int h) {            // 864 slots: 8ch x 6row x 18quad
        const float* base = xb + (size_t)h * 8 * HW;
        #pragma unroll
        for (int t = 0; t < 4; ++t) {
            if (tid + t * 256 < 864) {
                GLDS16(base + stB_goff[t], &XW[(tid + t * 256) * 4]);
            }
        }
    };

    stageB(0);                            // DMA hides under metadata below

    int   moff[3][2];
    int   lidx0[3], lidx1[3];
    f32x2 wAB[3], wCD[3];
    #pragma unroll
    for (int j = 0; j < 3; ++j) {
        moff[j][0] = 0; moff[j][1] = 0;
        lidx0[j] = -1; lidx1[j] = 0;
        wAB[j] = (f32x2){0.f, 0.f}; wCD[j] = (f32x2){0.f, 0.f};
        int s = tid + j * 256;
        if (s < 576) {
            int k = s >> 6, p = s & 63;
            int wo = wo0 + p;
            int ky = k / 3, kx = k % 3;
            float dy = offs_l[(2 * k) * 64 + p];
            float dx = offs_l[(2 * k + 1) * 64 + p];
            float mk = offs_l[(18 + k) * 64 + p];
            float py  = (float)(ho - 1 + ky) + dy;
            float pxf = (float)(wo - 1 + kx) + dx;
            float fy = floorf(py), fx = floorf(pxf);
            float ly = py - fy, lx = pxf - fx;
            int y0 = (int)fy, x0 = (int)fx;
            int y1 = y0 + 1,  x1 = x0 + 1;
            bool vy0 = (y0 >= 0) && (y0 < H);
            bool vy1 = (y1 >= 0) && (y1 < H);
            bool vx0 = (x0 >= 0) && (x0 < W);
            bool vx1 = (x1 >= 0) && (x1 < W);
            float w0 = (vy0 && vx0) ? (1.f - ly) * (1.f - lx) * mk : 0.f;
            float w1 = (vy0 && vx1) ? (1.f - ly) * lx * mk : 0.f;
            float w2 = (vy1 && vx0) ? ly * (1.f - lx) * mk : 0.f;
            float w3 = (vy1 && vx1) ? ly * lx * mk : 0.f;
            int lc = min(max(x0, 0), W - 2);
            bool sel = (x0 == lc);
            int r0 = min(max(y0, 0), H - 1);
            int r1 = min(max(y1, 0), H - 1);
            moff[j][0] = (r0 * W + lc) * 4;
            moff[j][1] = (r1 * W + lc) * 4;
            wAB[j].x = sel ? w0 : w1;  wAB[j].y = sel ? w1 : w0;
            wCD[j].x = sel ? w2 : w3;  wCD[j].y = sel ? w3 : w2;
            int u0 = r0 - (ho - 2);
            int u1 = r1 - (ho - 2);
            int vvv = lc - (wo0 - 4);
            bool fastp = ((unsigned)u0 < 6u) && ((unsigned)u1 < 6u)
                       && ((unsigned)vvv < 71u);
            lidx1[j] = u1 * 72 + vvv;
            lidx0[j] = fastp ? (u0 * 72 + vvv) : -1;
        }
    }
    __syncthreads();                      // offs_l reads done; XW(B0) ready

    if (tid < 128) {                      // re-zero pads clobbered by offs_l
        short8 z = {0,0,0,0,0,0,0,0};
        *(short8*)&S[(tid >> 1) * LDK + 144 + (tid & 1) * 8] = z;
    }

    f32x4 acc[4][2];
    #pragma unroll
    for (int i = 0; i < 4; ++i)
        #pragma unroll
        for (int j = 0; j < 2; ++j)
            acc[i][j] = (f32x4){0.f, 0.f, 0.f, 0.f};

    auto sampleB = [&](int h) {
        #pragma unroll
        for (int j = 0; j < 3; ++j) {
            int s = tid + j * 256;
            if (s < 576) {
                int k = s >> 6, p = s & 63;
                float va[8];
                f32x2 wab = wAB[j], wcd = wCD[j];
                if (lidx0[j] >= 0) {
                    int l0 = lidx0[j], l1 = lidx1[j];
                    #pragma unroll
                    for (int ci = 0; ci < 8; ++ci) {
                        const float* bp = &XW[ci * 432];
                        f32x2 A  = *(const f32x2a*)(bp + l0);   // ds_read2_b32
                        f32x2 Bv = *(const f32x2a*)(bp + l1);
                        f32x2 t = A * wab + Bv * wcd;           // v_pk_fma_f32
                        va[ci] = t.x + t.y;
                    }
                } else {
                    #pragma unroll
                    for (int ci = 0; ci < 8; ++ci) {
                        const char* pc = (const char*)(xb + (size_t)(h * 8 + ci) * HW);
                        f32x2 A  = *(const f32x2a*)(pc + moff[j][0]);
                        f32x2 Bv = *(const f32x2a*)(pc + moff[j][1]);
                        f32x2 t = A * wab + Bv * wcd;
                        va[ci] = t.x + t.y;
                    }
                }
                u32x4 pk;
                pk.x = pkbf16(va[0], va[1]);
                pk.y = pkbf16(va[2], va[3]);
                pk.z = pkbf16(va[4], va[5]);
                pk.w = pkbf16(va[6], va[7]);
                *(u32x4*)&S[p * LDK + k * 16 + (h & 1) * 8] = pk;
            }
        }
    };

    auto mfmaB = [&](int c) {
        #pragma unroll
        for (int ks = 0; ks < 5; ++ks) {
            short8 a[4];
            #pragma unroll
            for (int of = 0; of < 4; ++of) {
                int o = oh + of * 16 + row16;
                a[of] = *(const short8*)(wbf + o * WBF_COLS + c * 160 + ks * 32 + kq * 8);
            }
            #pragma unroll
            for (int pf = 0; pf < 2; ++pf) {
                int p = ph + pf * 16 + row16;
                short8 bfr = *(const short8*)&S[p * LDK + ks * 32 + kq * 8];
                #pragma unroll
                for (int of = 0; of < 4; ++of)
                    acc[of][pf] = __builtin_amdgcn_mfma_f32_16x16x32_bf16(
                        a[of], bfr, acc[of][pf], 0, 0, 0);
            }
        }
    };

    sampleB(0); __syncthreads();
    stageB(1); __syncthreads(); sampleB(1); __syncthreads();
    #pragma unroll 1
    for (int c = 0; c < 3; ++c) {
        stageB(2 * c + 2);     // DMA in flight under MFMA below
        mfmaB(c);
        __syncthreads();
        sampleB(2 * c + 2);
        __syncthreads();
        stageB(2 * c + 3);
        __syncthreads();
        sampleB(2 * c + 3);
        __syncthreads();
    }
    mfmaB(3);

    // ---- store: C/D layout col(px)=lane&15, row(o)=(lane>>4)*4+r ----
    #pragma unroll
    for (int of = 0; of < 4; ++of) {
        #pragma unroll
        for (int r = 0; r < 4; ++r) {
            int o = oh + of * 16 + kq * 4 + r;
            float* orow = out + ((b * COUT + o) * H + ho) * W;
            #pragma unroll
            for (int pf = 0; pf < 2; ++pf) {
                int wo = wo0 + ph + pf * 16 + row16;
                orow[wo] = acc[of][pf][r];
            }
        }
    }
}

// ---------------------------------------------------------------------------
extern "C" void kernel_launch(void* const* d_in, const int* in_sizes, int n_in,
                              void* d_out, int out_size, void* d_ws, size_t ws_size,
                              hipStream_t stream)
{
    const float* x      = (const float*)d_in[0];
    const float* w_off  = (const float*)d_in[1];
    const float* b_off  = (const float*)d_in[2];
    const float* w_mask = (const float*)d_in[3];
    const float* b_mask = (const float*)d_in[4];
    const float* weight = (const float*)d_in[5];
    float* out   = (float*)d_out;

    float* bcat  = (float*)d_ws;
    short* wbf   = (short*)(bcat + 32);
    short* wcv   = wbf + WBF_SHORTS;

    prep_wcv<<<dim3((WCV_SHORTS + 255) / 256), 256, 0, stream>>>(
        w_off, b_off, w_mask, b_mask, wcv, bcat);
    prep_wbf<<<dim3((WBF_SHORTS + 255) / 256), 256, 0, stream>>>(weight, wbf);
    fused5_kernel<<<dim3(1024), 256, 0, stream>>>(x, wcv, wbf, bcat, out);
}

// Round 18
// 81.339 us; speedup vs baseline: 1.2628x; 1.2628x over previous
//
#include <hip/hip_runtime.h>
#include <math.h>

#define B 4
#define CIN 64
#define H 128
#define W 128
#define COUT 128
#define KK 9
#define HW (H*W)

#define WBF_COLS 640                 // 4 chunks x 160 (144 real + 16 zero)
#define WBF_SHORTS (COUT*WBF_COLS)
#define WCV_SHORTS (32*640)          // offmask conv weights, bf16, K-padded
#define LDK 168                      // LDS k-stride (shorts); 336B row stride

typedef __attribute__((ext_vector_type(8))) short short8;
typedef __attribute__((ext_vector_type(4))) float f32x4;
typedef __attribute__((ext_vector_type(2))) float f32x2;
typedef f32x2 __attribute__((aligned(4))) f32x2a;   // align-4 float2 load

// global->LDS DMA: 16B per lane, dest = wave-uniform base + lane*16.
#define GLDS16(g, l) __builtin_amdgcn_global_load_lds(                        \
    (__attribute__((address_space(1))) void*)(g),                             \
    (__attribute__((address_space(3))) void*)(l), 16, 0, 0)

__device__ __forceinline__ unsigned short f2bf(float f) {
    unsigned int u = __float_as_uint(f);
    u += 0x7fffu + ((u >> 16) & 1u);
    return (unsigned short)(u >> 16);
}

// ---------------------------------------------------------------------------
// prep_all: both weight preps in ONE launch (saves a launch + gap).
//  blocks [0,320):   wbf[o][cb*160 + tap*16 + ci] bf16, pads zero
//  blocks [320,400): wcv[f(32)][same layout] bf16 + bcat biases
// ---------------------------------------------------------------------------
__global__ void prep_all(const float* __restrict__ wgt,
                         const float* __restrict__ w_off, const float* __restrict__ b_off,
                         const float* __restrict__ w_mask, const float* __restrict__ b_mask,
                         short* __restrict__ wbf, short* __restrict__ wcv,
                         float* __restrict__ bcat)
{
    int idx = blockIdx.x * 256 + threadIdx.x;
    if (idx < WBF_SHORTS) {
        int o  = idx / WBF_COLS;
        int kp = idx % WBF_COLS;
        int cb = kp / 160, r = kp % 160;
        float v = 0.f;
        if (r < 144) {
            int tap = r >> 4;
            int c   = cb * 16 + (r & 15);
            v = wgt[(o * CIN + c) * KK + tap];
        }
        wbf[idx] = (short)f2bf(v);
    } else {
        int j = idx - WBF_SHORTS;
        if (j < WCV_SHORTS) {
            int f  = j / 640;
            int kp = j % 640;
            int cb = kp / 160, r = kp % 160;
            float v = 0.f;
            if (r < 144) {
                int tap = r >> 4;
                int c   = cb * 16 + (r & 15);
                if (f < 18)      v = w_off[(f * CIN + c) * 9 + tap];
                else if (f < 27) v = w_mask[((f - 18) * CIN + c) * 9 + tap];
            }
            wcv[j] = (short)f2bf(v);
        }
        if (blockIdx.x == WBF_SHORTS / 256 && threadIdx.x < 32) {
            int f = threadIdx.x;
            float bv = 0.f;
            if (f < 18) bv = b_off[f];
            else if (f < 27) bv = b_mask[f - 18];
            bcat[f] = bv;
        }
    }
}

// ---------------------------------------------------------------------------
// fused4 (R16-validated, 80.4us): phase A = 27-filter conv via MFMA in
// 16-ch chunks (A's 16x3x72 window = B's 8x6x72 window = 13,824 B, XW
// reinterpreted); phase B = deform sample + MFMA einsum in 8-ch halves.
// offs/mask live only in LDS (aliased into S). DMA staging throughout;
// paired f32x2 LDS bilinear reads (ds_read2_b32); pk-math bilinear
// (v_pk_fma_f32); scalar-cast bf16 packing (m240/R17: do NOT hand-write
// cvt_pk -- it blocks the compiler's software pipelining, -25%).
// LDS 35,328 B -> 4 blocks/CU (R15: occupancy > barrier count).
// XCD band swizzle; no chunk stagger (R8); launch_bounds(256,2) so the
// allocator targets <=128 VGPR (R12: bound 4 -> 64 VGPR + spill).
// ---------------------------------------------------------------------------
__global__ __launch_bounds__(256, 2) void fused4_kernel(
    const float* __restrict__ x, const short* __restrict__ wcv,
    const short* __restrict__ wbf, const float* __restrict__ bcat,
    float* __restrict__ out)
{
    const int bid = blockIdx.x;
    const int T = (bid & 7) * 128 + (bid >> 3);
    const int wo0 = (T & 1) * 64;
    const int ho  = (T >> 1) & 127;
    const int b   = T >> 8;
    const int tid  = threadIdx.x;
    const int lane = tid & 63;
    const int wv   = tid >> 6;
    const int oh   = (wv & 1) * 64;
    const int ph   = (wv >> 1) * 32;
    const int row16 = lane & 15, kq = lane >> 4;

    __shared__ __align__(16) float XW[3456];          // 13,824 B
                                                      //  A: [ci16][row3][72]
                                                      //  B: [ci8][row6][72]
    __shared__ __align__(16) short S[64 * LDK];       // 21,504 B
    float* offs_l = (float*)S;                        // phase-A out: 27*64 f32

    const float* xb = x + (size_t)b * CIN * HW;

    // =======================================================================
    // Phase A: 27-filter conv via MFMA, 16-ch chunks (4 chunks of K=144).
    // =======================================================================
    int stA_goff[4];
    #pragma unroll
    for (int t = 0; t < 4; ++t) {
        int idx = tid + t * 256;
        int ci = idx / 54, rem = idx % 54, row = rem / 18, q = rem % 18;
        int ys = min(max(ho - 1 + row, 0), H - 1);
        int g0 = wo0 - 4 + q * 4;
        int g0c = min(max(g0, 0), W - 4);
        stA_goff[t] = ci * HW + ys * W + g0c;
    }
    auto stageA = [&](int c) {        // 864 slots: 16ch x 3row x 18quad
        const float* base = xb + (size_t)c * 16 * HW;
        #pragma unroll
        for (int t = 0; t < 4; ++t) {
            if (tid + t * 256 < 864) {
                GLDS16(base + stA_goff[t], &XW[(tid + t * 256) * 4]);
            }
        }
    };

    if (tid < 128) {                      // zero K-pad [144,160)
        short8 z = {0,0,0,0,0,0,0,0};
        *(short8*)&S[(tid >> 1) * LDK + 144 + (tid & 1) * 8] = z;
    }
    stageA(0);                            // DMA in flight under metadata below

    int bidx[3];                           // im2col src offset; -1 = zero
    #pragma unroll
    for (int j = 0; j < 3; ++j) {
        bidx[j] = -1;
        int s = tid + j * 256;
        if (s < 576) {
            int k = s >> 6, p = s & 63;
            int ky = k / 3, kx = k % 3;
            bool ok = ((unsigned)(ho - 1 + ky) < (unsigned)H)
                   && ((unsigned)(wo0 + p - 1 + kx) < (unsigned)W);
            if (ok) bidx[j] = ky * 72 + (p + 3 + kx);
        }
    }
    // phase-B staging offsets (computed here to hide stageA(0))
    int stB_goff[4];
    #pragma unroll
    for (int t = 0; t < 4; ++t) {
        int idx = tid + t * 256;
        int ci = idx / 108, rem = idx % 108, row = rem / 18, q = rem % 18;
        int ys = min(max(ho - 2 + row, 0), H - 1);
        int g0 = wo0 - 4 + q * 4;
        int g0c = min(max(g0, 0), W - 4);
        stB_goff[t] = ci * HW + ys * W + g0c;
    }
    __syncthreads();                      // XW(A0) ready, pads zeroed

    f32x4 acc2[2];
    acc2[0] = (f32x4){0.f, 0.f, 0.f, 0.f};
    acc2[1] = (f32x4){0.f, 0.f, 0.f, 0.f};

    auto buildA = [&]() {                 // 16 ci per slot (both parities)
        #pragma unroll
        for (int j = 0; j < 3; ++j) {
            int s = tid + j * 256;
            if (s < 576) {
                int k = s >> 6, p = s & 63;
                #pragma unroll
                for (int h2 = 0; h2 < 2; ++h2) {
                    short8 sv = {0,0,0,0,0,0,0,0};
                    if (bidx[j] >= 0) {
                        #pragma unroll
                        for (int c8 = 0; c8 < 8; ++c8)
                            sv[c8] = (short)f2bf(XW[(h2 * 8 + c8) * 216 + bidx[j]]);
                    }
                    *(short8*)&S[p * LDK + k * 16 + h2 * 8] = sv;
                }
            }
        }
    };
    auto mfmaA = [&](int c) {
        #pragma unroll
        for (int ks = 0; ks < 5; ++ks) {
            short8 a0 = *(const short8*)(wcv + (row16)      * 640 + c * 160 + ks * 32 + kq * 8);
            short8 a1 = *(const short8*)(wcv + (16 + row16) * 640 + c * 160 + ks * 32 + kq * 8);
            short8 bfr = *(const short8*)&S[(wv * 16 + row16) * LDK + ks * 32 + kq * 8];
            acc2[0] = __builtin_amdgcn_mfma_f32_16x16x32_bf16(a0, bfr, acc2[0], 0, 0, 0);
            acc2[1] = __builtin_amdgcn_mfma_f32_16x16x32_bf16(a1, bfr, acc2[1], 0, 0, 0);
        }
    };

    buildA();
    __syncthreads();                      // S(0) ready; XW reads done
    #pragma unroll 1
    for (int c = 0; c < 3; ++c) {
        stageA(c + 1);                    // DMA drains under MFMA
        mfmaA(c);
        __syncthreads();                  // DMA done; S reads done
        buildA();
        __syncthreads();                  // S ready; XW reads done
    }
    mfmaA(3);
    __syncthreads();                      // all S reads done -> S reusable

    // conv epilogue: bias + sigmoid -> offs_l (LDS, aliases S)
    {
        const int pxl = wv * 16 + row16;
        #pragma unroll
        for (int of = 0; of < 2; ++of) {
            #pragma unroll
            for (int r = 0; r < 4; ++r) {
                int f = of * 16 + kq * 4 + r;
                if (f < 27) {
                    float v = acc2[of][r] + bcat[f];
                    if (f >= 18) v = 1.f / (1.f + expf(-v));
                    offs_l[f * 64 + pxl] = v;
                }
            }
        }
    }
    __syncthreads();                      // offs_l visible

    // =======================================================================
    // Phase B: deform sample + MFMA einsum, 8-ch halves.
    // =======================================================================
    auto stageB = [&](int h) {            // 864 slots: 8ch x 6row x 18quad
        const float* base = xb + (size_t)h * 8 * HW;
        #pragma unroll
        for (int t = 0; t < 4; ++t) {
            if (tid + t * 256 < 864) {
                GLDS16(base + stB_goff[t], &XW[(tid + t * 256) * 4]);
            }
        }
    };

    stageB(0);                            // DMA hides under metadata below

    int   moff[3][2];
    int   lidx0[3], lidx1[3];
    f32x2 wAB[3], wCD[3];
    #pragma unroll
    for (int j = 0; j < 3; ++j) {
        moff[j][0] = 0; moff[j][1] = 0;
        lidx0[j] = -1; lidx1[j] = 0;
        wAB[j] = (f32x2){0.f, 0.f}; wCD[j] = (f32x2){0.f, 0.f};
        int s = tid + j * 256;
        if (s < 576) {
            int k = s >> 6, p = s & 63;
            int wo = wo0 + p;
            int ky = k / 3, kx = k % 3;
            float dy = offs_l[(2 * k) * 64 + p];
            float dx = offs_l[(2 * k + 1) * 64 + p];
            float mk = offs_l[(18 + k) * 64 + p];
            float py  = (float)(ho - 1 + ky) + dy;
            float pxf = (float)(wo - 1 + kx) + dx;
            float fy = floorf(py), fx = floorf(pxf);
            float ly = py - fy, lx = pxf - fx;
            int y0 = (int)fy, x0 = (int)fx;
            int y1 = y0 + 1,  x1 = x0 + 1;
            bool vy0 = (y0 >= 0) && (y0 < H);
            bool vy1 = (y1 >= 0) && (y1 < H);
            bool vx0 = (x0 >= 0) && (x0 < W);
            bool vx1 = (x1 >= 0) && (x1 < W);
            float w0 = (vy0 && vx0) ? (1.f - ly) * (1.f - lx) * mk : 0.f;
            float w1 = (vy0 && vx1) ? (1.f - ly) * lx * mk : 0.f;
            float w2 = (vy1 && vx0) ? ly * (1.f - lx) * mk : 0.f;
            float w3 = (vy1 && vx1) ? ly * lx * mk : 0.f;
            int lc = min(max(x0, 0), W - 2);
            bool sel = (x0 == lc);
            int r0 = min(max(y0, 0), H - 1);
            int r1 = min(max(y1, 0), H - 1);
            moff[j][0] = (r0 * W + lc) * 4;
            moff[j][1] = (r1 * W + lc) * 4;
            wAB[j].x = sel ? w0 : w1;  wAB[j].y = sel ? w1 : w0;
            wCD[j].x = sel ? w2 : w3;  wCD[j].y = sel ? w3 : w2;
            int u0 = r0 - (ho - 2);
            int u1 = r1 - (ho - 2);
            int vvv = lc - (wo0 - 4);
            bool fastp = ((unsigned)u0 < 6u) && ((unsigned)u1 < 6u)
                       && ((unsigned)vvv < 71u);
            lidx1[j] = u1 * 72 + vvv;
            lidx0[j] = fastp ? (u0 * 72 + vvv) : -1;
        }
    }
    __syncthreads();                      // offs_l reads done; XW(B0) ready

    if (tid < 128) {                      // re-zero pads clobbered by offs_l
        short8 z = {0,0,0,0,0,0,0,0};
        *(short8*)&S[(tid >> 1) * LDK + 144 + (tid & 1) * 8] = z;
    }

    f32x4 acc[4][2];
    #pragma unroll
    for (int i = 0; i < 4; ++i)
        #pragma unroll
        for (int j = 0; j < 2; ++j)
            acc[i][j] = (f32x4){0.f, 0.f, 0.f, 0.f};

    auto sampleB = [&](int h) {
        #pragma unroll
        for (int j = 0; j < 3; ++j) {
            int s = tid + j * 256;
            if (s < 576) {
                int k = s >> 6, p = s & 63;
                float va[8];
                f32x2 wab = wAB[j], wcd = wCD[j];
                if (lidx0[j] >= 0) {
                    int l0 = lidx0[j], l1 = lidx1[j];
                    #pragma unroll
                    for (int ci = 0; ci < 8; ++ci) {
                        const float* bp = &XW[ci * 432];
                        f32x2 A  = *(const f32x2a*)(bp + l0);   // ds_read2_b32
                        f32x2 Bv = *(const f32x2a*)(bp + l1);
                        f32x2 t = A * wab + Bv * wcd;           // v_pk_fma_f32
                        va[ci] = t.x + t.y;
                    }
                } else {
                    #pragma unroll
                    for (int ci = 0; ci < 8; ++ci) {
                        const char* pc = (const char*)(xb + (size_t)(h * 8 + ci) * HW);
                        f32x2 A  = *(const f32x2a*)(pc + moff[j][0]);
                        f32x2 Bv = *(const f32x2a*)(pc + moff[j][1]);
                        f32x2 t = A * wab + Bv * wcd;
                        va[ci] = t.x + t.y;
                    }
                }
                short8 sv;
                #pragma unroll
                for (int ci = 0; ci < 8; ++ci) sv[ci] = (short)f2bf(va[ci]);
                *(short8*)&S[p * LDK + k * 16 + (h & 1) * 8] = sv;
            }
        }
    };

    auto mfmaB = [&](int c) {
        #pragma unroll
        for (int ks = 0; ks < 5; ++ks) {
            short8 a[4];
            #pragma unroll
            for (int of = 0; of < 4; ++of) {
                int o = oh + of * 16 + row16;
                a[of] = *(const short8*)(wbf + o * WBF_COLS + c * 160 + ks * 32 + kq * 8);
            }
            #pragma unroll
            for (int pf = 0; pf < 2; ++pf) {
                int p = ph + pf * 16 + row16;
                short8 bfr = *(const short8*)&S[p * LDK + ks * 32 + kq * 8];
                #pragma unroll
                for (int of = 0; of < 4; ++of)
                    acc[of][pf] = __builtin_amdgcn_mfma_f32_16x16x32_bf16(
                        a[of], bfr, acc[of][pf], 0, 0, 0);
            }
        }
    };

    sampleB(0); __syncthreads();
    stageB(1); __syncthreads(); sampleB(1); __syncthreads();
    #pragma unroll 1
    for (int c = 0; c < 3; ++c) {
        stageB(2 * c + 2);     // DMA in flight under MFMA below
        mfmaB(c);
        __syncthreads();
        sampleB(2 * c + 2);
        __syncthreads();
        stageB(2 * c + 3);
        __syncthreads();
        sampleB(2 * c + 3);
        __syncthreads();
    }
    mfmaB(3);

    // ---- store: C/D layout col(px)=lane&15, row(o)=(lane>>4)*4+r ----
    #pragma unroll
    for (int of = 0; of < 4; ++of) {
        #pragma unroll
        for (int r = 0; r < 4; ++r) {
            int o = oh + of * 16 + kq * 4 + r;
            float* orow = out + ((b * COUT + o) * H + ho) * W;
            #pragma unroll
            for (int pf = 0; pf < 2; ++pf) {
                int wo = wo0 + ph + pf * 16 + row16;
                orow[wo] = acc[of][pf][r];
            }
        }
    }
}

// ---------------------------------------------------------------------------
extern "C" void kernel_launch(void* const* d_in, const int* in_sizes, int n_in,
                              void* d_out, int out_size, void* d_ws, size_t ws_size,
                              hipStream_t stream)
{
    const float* x      = (const float*)d_in[0];
    const float* w_off  = (const float*)d_in[1];
    const float* b_off  = (const float*)d_in[2];
    const float* w_mask = (const float*)d_in[3];
    const float* b_mask = (const float*)d_in[4];
    const float* weight = (const float*)d_in[5];
    float* out   = (float*)d_out;

    float* bcat  = (float*)d_ws;
    short* wbf   = (short*)(bcat + 32);
    short* wcv   = wbf + WBF_SHORTS;

    prep_all<<<dim3((WBF_SHORTS + WCV_SHORTS) / 256), 256, 0, stream>>>(
        weight, w_off, b_off, w_mask, b_mask, wbf, wcv, bcat);
    fused4_kernel<<<dim3(1024), 256, 0, stream>>>(x, wcv, wbf, bcat, out);
}

// Round 19
// 81.218 us; speedup vs baseline: 1.2647x; 1.0015x over previous
//
#include <hip/hip_runtime.h>
#include <math.h>

#define B 4
#define CIN 64
#define H 128
#define W 128
#define COUT 128
#define KK 9
#define HW (H*W)

#define WBF_COLS 640                 // 4 chunks x 160 (144 real + 16 zero)
#define WBF_SHORTS (COUT*WBF_COLS)
#define WCV_SHORTS (32*640)          // offmask conv weights, bf16, K-padded
#define LDK 168                      // LDS k-stride (shorts); 336B row stride

typedef __attribute__((ext_vector_type(8))) short short8;
typedef __attribute__((ext_vector_type(4))) float f32x4;
typedef __attribute__((ext_vector_type(2))) float f32x2;
typedef f32x2 __attribute__((aligned(4))) f32x2a;   // align-4 float2 load

// global->LDS DMA: 16B per lane, dest = wave-uniform base + lane*16.
#define GLDS16(g, l) __builtin_amdgcn_global_load_lds(                        \
    (__attribute__((address_space(1))) void*)(g),                             \
    (__attribute__((address_space(3))) void*)(l), 16, 0, 0)

__device__ __forceinline__ unsigned short f2bf(float f) {
    unsigned int u = __float_as_uint(f);
    u += 0x7fffu + ((u >> 16) & 1u);
    return (unsigned short)(u >> 16);
}

// ---------------------------------------------------------------------------
// prep_all: both weight preps in ONE launch.
//  blocks [0,320):   wbf[o][cb*160 + tap*16 + ci] bf16, pads zero
//  blocks [320,400): wcv[f(32)][same layout] bf16 + bcat biases
// ---------------------------------------------------------------------------
__global__ void prep_all(const float* __restrict__ wgt,
                         const float* __restrict__ w_off, const float* __restrict__ b_off,
                         const float* __restrict__ w_mask, const float* __restrict__ b_mask,
                         short* __restrict__ wbf, short* __restrict__ wcv,
                         float* __restrict__ bcat)
{
    int idx = blockIdx.x * 256 + threadIdx.x;
    if (idx < WBF_SHORTS) {
        int o  = idx / WBF_COLS;
        int kp = idx % WBF_COLS;
        int cb = kp / 160, r = kp % 160;
        float v = 0.f;
        if (r < 144) {
            int tap = r >> 4;
            int c   = cb * 16 + (r & 15);
            v = wgt[(o * CIN + c) * KK + tap];
        }
        wbf[idx] = (short)f2bf(v);
    } else {
        int j = idx - WBF_SHORTS;
        if (j < WCV_SHORTS) {
            int f  = j / 640;
            int kp = j % 640;
            int cb = kp / 160, r = kp % 160;
            float v = 0.f;
            if (r < 144) {
                int tap = r >> 4;
                int c   = cb * 16 + (r & 15);
                if (f < 18)      v = w_off[(f * CIN + c) * 9 + tap];
                else if (f < 27) v = w_mask[((f - 18) * CIN + c) * 9 + tap];
            }
            wcv[j] = (short)f2bf(v);
        }
        if (blockIdx.x == WBF_SHORTS / 256 && threadIdx.x < 32) {
            int f = threadIdx.x;
            float bv = 0.f;
            if (f < 18) bv = b_off[f];
            else if (f < 27) bv = b_mask[f - 18];
            bcat[f] = bv;
        }
    }
}

// ---------------------------------------------------------------------------
// fused4 (R18-validated, 80.5us) + s_setprio(1) around the MFMA clusters
// (T5). Regime: 4 independent blocks/CU drift out of phase, so an
// MFMA-entering wave competes with neighbors' sample/stage DS+VALU issue --
// priority compresses the mfma phases (attn-regime +4-7%; null only in
// barrier-lockstep single-block regimes).
// Everything else byte-identical to R18:
//  - phase A: 27-filter conv via MFMA, 16-ch chunks, offs/mask -> LDS only
//  - phase B: deform sample + MFMA einsum, 8-ch halves
//  - DMA staging, ds_read2 paired bilinear, pk-math, scalar-cast packing
//    (R17: hand-written cvt_pk asm blocks compiler pipelining, -25%)
//  - LDS 35,328 B -> 4 blocks/CU (R15: occupancy > barrier count)
//  - XCD band swizzle, no stagger (R8), launch_bounds(256,2) (R12 spill fix)
// ---------------------------------------------------------------------------
__global__ __launch_bounds__(256, 2) void fused4_kernel(
    const float* __restrict__ x, const short* __restrict__ wcv,
    const short* __restrict__ wbf, const float* __restrict__ bcat,
    float* __restrict__ out)
{
    const int bid = blockIdx.x;
    const int T = (bid & 7) * 128 + (bid >> 3);
    const int wo0 = (T & 1) * 64;
    const int ho  = (T >> 1) & 127;
    const int b   = T >> 8;
    const int tid  = threadIdx.x;
    const int lane = tid & 63;
    const int wv   = tid >> 6;
    const int oh   = (wv & 1) * 64;
    const int ph   = (wv >> 1) * 32;
    const int row16 = lane & 15, kq = lane >> 4;

    __shared__ __align__(16) float XW[3456];          // 13,824 B
                                                      //  A: [ci16][row3][72]
                                                      //  B: [ci8][row6][72]
    __shared__ __align__(16) short S[64 * LDK];       // 21,504 B
    float* offs_l = (float*)S;                        // phase-A out: 27*64 f32

    const float* xb = x + (size_t)b * CIN * HW;

    // =======================================================================
    // Phase A: 27-filter conv via MFMA, 16-ch chunks (4 chunks of K=144).
    // =======================================================================
    int stA_goff[4];
    #pragma unroll
    for (int t = 0; t < 4; ++t) {
        int idx = tid + t * 256;
        int ci = idx / 54, rem = idx % 54, row = rem / 18, q = rem % 18;
        int ys = min(max(ho - 1 + row, 0), H - 1);
        int g0 = wo0 - 4 + q * 4;
        int g0c = min(max(g0, 0), W - 4);
        stA_goff[t] = ci * HW + ys * W + g0c;
    }
    auto stageA = [&](int c) {        // 864 slots: 16ch x 3row x 18quad
        const float* base = xb + (size_t)c * 16 * HW;
        #pragma unroll
        for (int t = 0; t < 4; ++t) {
            if (tid + t * 256 < 864) {
                GLDS16(base + stA_goff[t], &XW[(tid + t * 256) * 4]);
            }
        }
    };

    if (tid < 128) {                      // zero K-pad [144,160)
        short8 z = {0,0,0,0,0,0,0,0};
        *(short8*)&S[(tid >> 1) * LDK + 144 + (tid & 1) * 8] = z;
    }
    stageA(0);                            // DMA in flight under metadata below

    int bidx[3];                           // im2col src offset; -1 = zero
    #pragma unroll
    for (int j = 0; j < 3; ++j) {
        bidx[j] = -1;
        int s = tid + j * 256;
        if (s < 576) {
            int k = s >> 6, p = s & 63;
            int ky = k / 3, kx = k % 3;
            bool ok = ((unsigned)(ho - 1 + ky) < (unsigned)H)
                   && ((unsigned)(wo0 + p - 1 + kx) < (unsigned)W);
            if (ok) bidx[j] = ky * 72 + (p + 3 + kx);
        }
    }
    // phase-B staging offsets (computed here to hide stageA(0))
    int stB_goff[4];
    #pragma unroll
    for (int t = 0; t < 4; ++t) {
        int idx = tid + t * 256;
        int ci = idx / 108, rem = idx % 108, row = rem / 18, q = rem % 18;
        int ys = min(max(ho - 2 + row, 0), H - 1);
        int g0 = wo0 - 4 + q * 4;
        int g0c = min(max(g0, 0), W - 4);
        stB_goff[t] = ci * HW + ys * W + g0c;
    }
    __syncthreads();                      // XW(A0) ready, pads zeroed

    f32x4 acc2[2];
    acc2[0] = (f32x4){0.f, 0.f, 0.f, 0.f};
    acc2[1] = (f32x4){0.f, 0.f, 0.f, 0.f};

    auto buildA = [&]() {                 // 16 ci per slot (both parities)
        #pragma unroll
        for (int j = 0; j < 3; ++j) {
            int s = tid + j * 256;
            if (s < 576) {
                int k = s >> 6, p = s & 63;
                #pragma unroll
                for (int h2 = 0; h2 < 2; ++h2) {
                    short8 sv = {0,0,0,0,0,0,0,0};
                    if (bidx[j] >= 0) {
                        #pragma unroll
                        for (int c8 = 0; c8 < 8; ++c8)
                            sv[c8] = (short)f2bf(XW[(h2 * 8 + c8) * 216 + bidx[j]]);
                    }
                    *(short8*)&S[p * LDK + k * 16 + h2 * 8] = sv;
                }
            }
        }
    };
    auto mfmaA = [&](int c) {
        __builtin_amdgcn_s_setprio(1);
        #pragma unroll
        for (int ks = 0; ks < 5; ++ks) {
            short8 a0 = *(const short8*)(wcv + (row16)      * 640 + c * 160 + ks * 32 + kq * 8);
            short8 a1 = *(const short8*)(wcv + (16 + row16) * 640 + c * 160 + ks * 32 + kq * 8);
            short8 bfr = *(const short8*)&S[(wv * 16 + row16) * LDK + ks * 32 + kq * 8];
            acc2[0] = __builtin_amdgcn_mfma_f32_16x16x32_bf16(a0, bfr, acc2[0], 0, 0, 0);
            acc2[1] = __builtin_amdgcn_mfma_f32_16x16x32_bf16(a1, bfr, acc2[1], 0, 0, 0);
        }
        __builtin_amdgcn_s_setprio(0);
    };

    buildA();
    __syncthreads();                      // S(0) ready; XW reads done
    #pragma unroll 1
    for (int c = 0; c < 3; ++c) {
        stageA(c + 1);                    // DMA drains under MFMA
        mfmaA(c);
        __syncthreads();                  // DMA done; S reads done
        buildA();
        __syncthreads();                  // S ready; XW reads done
    }
    mfmaA(3);
    __syncthreads();                      // all S reads done -> S reusable

    // conv epilogue: bias + sigmoid -> offs_l (LDS, aliases S)
    {
        const int pxl = wv * 16 + row16;
        #pragma unroll
        for (int of = 0; of < 2; ++of) {
            #pragma unroll
            for (int r = 0; r < 4; ++r) {
                int f = of * 16 + kq * 4 + r;
                if (f < 27) {
                    float v = acc2[of][r] + bcat[f];
                    if (f >= 18) v = 1.f / (1.f + expf(-v));
                    offs_l[f * 64 + pxl] = v;
                }
            }
        }
    }
    __syncthreads();                      // offs_l visible

    // =======================================================================
    // Phase B: deform sample + MFMA einsum, 8-ch halves.
    // =======================================================================
    auto stageB = [&](int h) {            // 864 slots: 8ch x 6row x 18quad
        const float* base = xb + (size_t)h * 8 * HW;
        #pragma unroll
        for (int t = 0; t < 4; ++t) {
            if (tid + t * 256 < 864) {
                GLDS16(base + stB_goff[t], &XW[(tid + t * 256) * 4]);
            }
        }
    };

    stageB(0);                            // DMA hides under metadata below

    int   moff[3][2];
    int   lidx0[3], lidx1[3];
    f32x2 wAB[3], wCD[3];
    #pragma unroll
    for (int j = 0; j < 3; ++j) {
        moff[j][0] = 0; moff[j][1] = 0;
        lidx0[j] = -1; lidx1[j] = 0;
        wAB[j] = (f32x2){0.f, 0.f}; wCD[j] = (f32x2){0.f, 0.f};
        int s = tid + j * 256;
        if (s < 576) {
            int k = s >> 6, p = s & 63;
            int wo = wo0 + p;
            int ky = k / 3, kx = k % 3;
            float dy = offs_l[(2 * k) * 64 + p];
            float dx = offs_l[(2 * k + 1) * 64 + p];
            float mk = offs_l[(18 + k) * 64 + p];
            float py  = (float)(ho - 1 + ky) + dy;
            float pxf = (float)(wo - 1 + kx) + dx;
            float fy = floorf(py), fx = floorf(pxf);
            float ly = py - fy, lx = pxf - fx;
            int y0 = (int)fy, x0 = (int)fx;
            int y1 = y0 + 1,  x1 = x0 + 1;
            bool vy0 = (y0 >= 0) && (y0 < H);
            bool vy1 = (y1 >= 0) && (y1 < H);
            bool vx0 = (x0 >= 0) && (x0 < W);
            bool vx1 = (x1 >= 0) && (x1 < W);
            float w0 = (vy0 && vx0) ? (1.f - ly) * (1.f - lx) * mk : 0.f;
            float w1 = (vy0 && vx1) ? (1.f - ly) * lx * mk : 0.f;
            float w2 = (vy1 && vx0) ? ly * (1.f - lx) * mk : 0.f;
            float w3 = (vy1 && vx1) ? ly * lx * mk : 0.f;
            int lc = min(max(x0, 0), W - 2);
            bool sel = (x0 == lc);
            int r0 = min(max(y0, 0), H - 1);
            int r1 = min(max(y1, 0), H - 1);
            moff[j][0] = (r0 * W + lc) * 4;
            moff[j][1] = (r1 * W + lc) * 4;
            wAB[j].x = sel ? w0 : w1;  wAB[j].y = sel ? w1 : w0;
            wCD[j].x = sel ? w2 : w3;  wCD[j].y = sel ? w3 : w2;
            int u0 = r0 - (ho - 2);
            int u1 = r1 - (ho - 2);
            int vvv = lc - (wo0 - 4);
            bool fastp = ((unsigned)u0 < 6u) && ((unsigned)u1 < 6u)
                       && ((unsigned)vvv < 71u);
            lidx1[j] = u1 * 72 + vvv;
            lidx0[j] = fastp ? (u0 * 72 + vvv) : -1;
        }
    }
    __syncthreads();                      // offs_l reads done; XW(B0) ready

    if (tid < 128) {                      // re-zero pads clobbered by offs_l
        short8 z = {0,0,0,0,0,0,0,0};
        *(short8*)&S[(tid >> 1) * LDK + 144 + (tid & 1) * 8] = z;
    }

    f32x4 acc[4][2];
    #pragma unroll
    for (int i = 0; i < 4; ++i)
        #pragma unroll
        for (int j = 0; j < 2; ++j)
            acc[i][j] = (f32x4){0.f, 0.f, 0.f, 0.f};

    auto sampleB = [&](int h) {
        #pragma unroll
        for (int j = 0; j < 3; ++j) {
            int s = tid + j * 256;
            if (s < 576) {
                int k = s >> 6, p = s & 63;
                float va[8];
                f32x2 wab = wAB[j], wcd = wCD[j];
                if (lidx0[j] >= 0) {
                    int l0 = lidx0[j], l1 = lidx1[j];
                    #pragma unroll
                    for (int ci = 0; ci < 8; ++ci) {
                        const float* bp = &XW[ci * 432];
                        f32x2 A  = *(const f32x2a*)(bp + l0);   // ds_read2_b32
                        f32x2 Bv = *(const f32x2a*)(bp + l1);
                        f32x2 t = A * wab + Bv * wcd;           // v_pk_fma_f32
                        va[ci] = t.x + t.y;
                    }
                } else {
                    #pragma unroll
                    for (int ci = 0; ci < 8; ++ci) {
                        const char* pc = (const char*)(xb + (size_t)(h * 8 + ci) * HW);
                        f32x2 A  = *(const f32x2a*)(pc + moff[j][0]);
                        f32x2 Bv = *(const f32x2a*)(pc + moff[j][1]);
                        f32x2 t = A * wab + Bv * wcd;
                        va[ci] = t.x + t.y;
                    }
                }
                short8 sv;
                #pragma unroll
                for (int ci = 0; ci < 8; ++ci) sv[ci] = (short)f2bf(va[ci]);
                *(short8*)&S[p * LDK + k * 16 + (h & 1) * 8] = sv;
            }
        }
    };

    auto mfmaB = [&](int c) {
        __builtin_amdgcn_s_setprio(1);
        #pragma unroll
        for (int ks = 0; ks < 5; ++ks) {
            short8 a[4];
            #pragma unroll
            for (int of = 0; of < 4; ++of) {
                int o = oh + of * 16 + row16;
                a[of] = *(const short8*)(wbf + o * WBF_COLS + c * 160 + ks * 32 + kq * 8);
            }
            #pragma unroll
            for (int pf = 0; pf < 2; ++pf) {
                int p = ph + pf * 16 + row16;
                short8 bfr = *(const short8*)&S[p * LDK + ks * 32 + kq * 8];
                #pragma unroll
                for (int of = 0; of < 4; ++of)
                    acc[of][pf] = __builtin_amdgcn_mfma_f32_16x16x32_bf16(
                        a[of], bfr, acc[of][pf], 0, 0, 0);
            }
        }
        __builtin_amdgcn_s_setprio(0);
    };

    sampleB(0); __syncthreads();
    stageB(1); __syncthreads(); sampleB(1); __syncthreads();
    #pragma unroll 1
    for (int c = 0; c < 3; ++c) {
        stageB(2 * c + 2);     // DMA in flight under MFMA below
        mfmaB(c);
        __syncthreads();
        sampleB(2 * c + 2);
        __syncthreads();
        stageB(2 * c + 3);
        __syncthreads();
        sampleB(2 * c + 3);
        __syncthreads();
    }
    mfmaB(3);

    // ---- store: C/D layout col(px)=lane&15, row(o)=(lane>>4)*4+r ----
    #pragma unroll
    for (int of = 0; of < 4; ++of) {
        #pragma unroll
        for (int r = 0; r < 4; ++r) {
            int o = oh + of * 16 + kq * 4 + r;
            float* orow = out + ((b * COUT + o) * H + ho) * W;
            #pragma unroll
            for (int pf = 0; pf < 2; ++pf) {
                int wo = wo0 + ph + pf * 16 + row16;
                orow[wo] = acc[of][pf][r];
            }
        }
    }
}

// ---------------------------------------------------------------------------
extern "C" void kernel_launch(void* const* d_in, const int* in_sizes, int n_in,
                              void* d_out, int out_size, void* d_ws, size_t ws_size,
                              hipStream_t stream)
{
    const float* x      = (const float*)d_in[0];
    const float* w_off  = (const float*)d_in[1];
    const float* b_off  = (const float*)d_in[2];
    const float* w_mask = (const float*)d_in[3];
    const float* b_mask = (const float*)d_in[4];
    const float* weight = (const float*)d_in[5];
    float* out   = (float*)d_out;

    float* bcat  = (float*)d_ws;
    short* wbf   = (short*)(bcat + 32);
    short* wcv   = wbf + WBF_SHORTS;

    prep_all<<<dim3((WBF_SHORTS + WCV_SHORTS) / 256), 256, 0, stream>>>(
        weight, w_off, b_off, w_mask, b_mask, wbf, wcv, bcat);
    fused4_kernel<<<dim3(1024), 256, 0, stream>>>(x, wcv, wbf, bcat, out);
}